// Round 3
// baseline (368.396 us; speedup 1.0000x reference)
//
#include <hip/hip_runtime.h>

#define NI 2048
#define NB 64
#define NC 32
#define DC 16
#define DI 8

static constexpr float SQ_EPS = 1e-7f;

// SSA vector type: first-class LLVM vector -> never an alloca, never scratch.
typedef float f8 __attribute__((ext_vector_type(8)));

// Routing pass v4 — v1's proven 256-thread codegen, 4 blocks/CU.
// v2/v3 post-mortem: 512-thread + amdgpu_waves_per_eu(4[,4]) never raised
// the 64-VGPR budget (VGPR_Count stayed 64, 223/250 MB spill traffic,
// dur 118 us). Abandoned. Instead keep v1's inner loop (108 VGPRs measured)
// and raise occupancy via MORE BLOCKS: stage 2 i-slots per round (8 rounds)
// -> wbuf 33.8 KB + per-round xbuf 1 KB = 34.8 KB LDS -> 4 blocks/CU
// x 4 waves = 16 waves/CU = 4/SIMD (v1: 2/SIMD, VALUBusy 37%,
// latency-bound at 47 us/pass). Register budget via standard
// __launch_bounds__(256, 4) = 128 VGPRs >= the 108 v1 needed.
// Per-wave arithmetic, ds_read count, W global loads, partial layout:
// all IDENTICAL to v1. Only barrier count doubles (16 vs 8), hidden by
// 4 co-resident independent blocks.
// Grid (128 i-blocks, 4 b-quarters) x 256 threads (4 waves).
// Wave w owns b-quad by*16 + w*4 + {0..3}; every wave sweeps all 16 i.
// Lane = (c = lane&31, dg = lane>>5).
// MODE 0: uniform coupling 1/32. MODE 1: logits = dot(u, veff),
// veff transposed [b][dg][c][8].
template <int MODE>
__global__ __launch_bounds__(256, 4)
void route_pass(
    const float* __restrict__ x, const float* __restrict__ W,
    const float* __restrict__ veff, float* __restrict__ partial)
{
    // W slots: float4 [slot 2][k10 16][kdg 2][c 32 + 1 pad] stride 33.
    __shared__ float4 wbuf[2112];   // 33.8 KB
    __shared__ float4 xbuf[64];     // [brel 16][4] = 2 i x 2 f4 per b, 1 KB

    const int tid   = threadIdx.x;
    const int wave  = tid >> 6;
    const int lane  = tid & 63;
    const int c     = lane & 31;
    const int dg    = lane >> 5;
    const int brel0 = wave * 4;
    const int b0    = blockIdx.y * 16 + brel0;    // wave's b-quad base

    f8 s0 = {}, s1 = {}, s2 = {}, s3 = {};

    // veff fragments for the 4 b's (MODE 1), transposed [b][dg][c][8]
    f8 va = {}, vb = {}, vc = {}, vd = {};
    if (MODE == 1) {
        va = *reinterpret_cast<const f8*>(veff + (((size_t)(b0+0)*2 + dg)*32 + c)*8);
        vb = *reinterpret_cast<const f8*>(veff + (((size_t)(b0+1)*2 + dg)*32 + c)*8);
        vc = *reinterpret_cast<const f8*>(veff + (((size_t)(b0+2)*2 + dg)*32 + c)*8);
        vd = *reinterpret_cast<const f8*>(veff + (((size_t)(b0+3)*2 + dg)*32 + c)*8);
    }

    for (int rnd = 0; rnd < 8; ++rnd) {
        const int i0 = blockIdx.x * 16 + rnd * 2;
        __syncthreads();               // previous round's readers done
        // ---- stage W: 2 i-rows x 32 c = 64 rows x 512 B (coalesced)
        {
            const int k   = tid & 31;         // float4 within a (c,i) row
            const int p0  = tid >> 5;         // 0..7
            const int k10 = k & 15, kdg = k >> 4;
#pragma unroll
            for (int r = 0; r < 8; ++r) {
                const int row = r * 8 + p0;   // 0..63
                const int cc  = row >> 1;
                const int sub = row & 1;      // i-slot
                wbuf[((sub * 16 + k10) * 2 + kdg) * 33 + cc] =
                    reinterpret_cast<const float4*>(W)[
                        ((size_t)cc * NI + i0 + sub) * 32 + k];
            }
        }
        // ---- stage x: 16 b x 2 i x 8 f = 64 float4
        if (tid < 64) {
            const int brel = tid >> 2;
            const int q    = tid & 3;
            xbuf[tid] = reinterpret_cast<const float4*>(x)[
                ((size_t)(blockIdx.y * 16 + brel) * NI + i0) * 2 + q];
        }
        __syncthreads();

#pragma unroll
        for (int il = 0; il < 2; ++il) {
            // x broadcast reads (wave-uniform LDS addresses)
            const float4 xa0 = xbuf[(brel0+0)*4 + il*2], xa1 = xbuf[(brel0+0)*4 + il*2+1];
            const float4 xb0 = xbuf[(brel0+1)*4 + il*2], xb1 = xbuf[(brel0+1)*4 + il*2+1];
            const float4 xc0 = xbuf[(brel0+2)*4 + il*2], xc1 = xbuf[(brel0+2)*4 + il*2+1];
            const float4 xd0 = xbuf[(brel0+3)*4 + il*2], xd1 = xbuf[(brel0+3)*4 + il*2+1];

            f8 u0 = {}, u1 = {}, u2 = {}, u3 = {};
#pragma unroll
            for (int dd = 0; dd < 8; ++dd) {
                const float4 wl = wbuf[((il*16 + dd*2    )*2 + dg)*33 + c];
                const float4 wh = wbuf[((il*16 + dd*2 + 1)*2 + dg)*33 + c];
                u0[dd] = wl.x*xa0.x + wl.y*xa0.y + wl.z*xa0.z + wl.w*xa0.w
                       + wh.x*xa1.x + wh.y*xa1.y + wh.z*xa1.z + wh.w*xa1.w;
                u1[dd] = wl.x*xb0.x + wl.y*xb0.y + wl.z*xb0.z + wl.w*xb0.w
                       + wh.x*xb1.x + wh.y*xb1.y + wh.z*xb1.z + wh.w*xb1.w;
                u2[dd] = wl.x*xc0.x + wl.y*xc0.y + wl.z*xc0.z + wl.w*xc0.w
                       + wh.x*xc1.x + wh.y*xc1.y + wh.z*xc1.z + wh.w*xc1.w;
                u3[dd] = wl.x*xd0.x + wl.y*xd0.y + wl.z*xd0.z + wl.w*xd0.w
                       + wh.x*xd1.x + wh.y*xd1.y + wh.z*xd1.z + wh.w*xd1.w;
            }

            if (MODE == 0) {
                const float cu = 1.0f / 32.0f;
                s0 += u0 * cu; s1 += u1 * cu; s2 += u2 * cu; s3 += u3 * cu;
            } else {
                // Pair-softmax: lower 32-half reduces the even b, upper the
                // odd b, concurrently; one xor-32 merge in, one xor-32
                // coef-swap out. 12 shuffles + 1 exp per pair.
#pragma unroll
                for (int pr = 0; pr < 2; ++pr) {
                    const f8& ue = pr ? u2 : u0;
                    const f8& uo = pr ? u3 : u1;
                    const f8& ve = pr ? vc : va;
                    const f8& vo = pr ? vd : vb;
                    float pe = 0.0f, po = 0.0f;
#pragma unroll
                    for (int k = 0; k < 8; ++k) {
                        pe += ue[k] * ve[k];
                        po += uo[k] * vo[k];
                    }
                    // route partial of the OTHER half's b across, keep mine
                    const float send = (dg == 0) ? po : pe;
                    const float recv = __shfl_xor(send, 32);
                    float a = ((dg == 0) ? pe : po) + recv;  // full logit
                    float m = a;
#pragma unroll
                    for (int off = 16; off >= 1; off >>= 1)
                        m = fmaxf(m, __shfl_xor(m, off));
                    const float e = __expf(a - m);
                    float t = e;
#pragma unroll
                    for (int off = 16; off >= 1; off >>= 1)
                        t += __shfl_xor(t, off);
                    const float mine  = e / t;
                    const float other = __shfl_xor(mine, 32);
                    const float ce = (dg == 0) ? mine : other;
                    const float co = (dg == 0) ? other : mine;
                    if (pr == 0) { s0 += u0 * ce; s1 += u1 * co; }
                    else         { s2 += u2 * ce; s3 += u3 * co; }
                }
            }
        }
    }

    // ---- flush the wave's four s-partials (plain coalesced 32 B stores)
    // partial floats: [pblk 512][brel 16][dg 2][c 32][8]
    {
        const int pblk = blockIdx.y * gridDim.x + blockIdx.x;   // 0..511
        float* gp = partial +
            (((size_t)pblk * 16 + brel0) * 128 + dg * 64 + c * 2) * 4;
        *reinterpret_cast<f8*>(gp)        = s0;
        *reinterpret_cast<f8*>(gp +  512) = s1;
        *reinterpret_cast<f8*>(gp + 1024) = s2;
        *reinterpret_cast<f8*>(gp + 1536) = s3;
    }
}

// Fused 128-way partial reduction + squash, float4-vectorized.
// 64 blocks x 512 threads: tid -> (ibq = tid>>7 sums 32 of the 128 i-block
// slabs; sub = tid&127 -> (c = (sub>>2)&31, dq = sub&3)). 4-way LDS tree
// then squash on tid<128.
// phase 1: veff  = NI * squash(s)   (transposed layout [b][dg][c][8])
// phase 2: veff += NI * squash(s)
// phase 3: out   = squash(s)        (canonical [b][c][d])
__global__ __launch_bounds__(512) void reduce_squash(
    const float* __restrict__ partial, float* __restrict__ veff,
    float* __restrict__ out, int phase)
{
    __shared__ float4 red[512];
    const int b   = blockIdx.x;
    const int sub = threadIdx.x & 127;
    const int ibq = threadIdx.x >> 7;        // i-block quarter
    const int c   = (sub >> 2) & 31;
    const int dq  = sub & 3;                 // d-quad: d = dq*4 + j

    // slab layout: [by*128 + ib][brel 16][dg 2][c 32][8]
    const float* base = partial
        + ((size_t)(b >> 4) * 2048 + (b & 15)) * 512
        + (dq >> 1) * 256 + c * 8 + (dq & 1) * 4
        + (size_t)ibq * 32 * 8192;
    float4 acc = make_float4(0.f, 0.f, 0.f, 0.f);
#pragma unroll 8
    for (int ib = 0; ib < 32; ++ib) {
        const float4 p = *reinterpret_cast<const float4*>(base + (size_t)ib * 8192);
        acc.x += p.x; acc.y += p.y; acc.z += p.z; acc.w += p.w;
    }
    red[threadIdx.x] = acc;
    __syncthreads();
    if (threadIdx.x < 128) {
        const float4 a1 = red[sub + 128];
        const float4 a2 = red[sub + 256];
        const float4 a3 = red[sub + 384];
        acc.x += a1.x + a2.x + a3.x;
        acc.y += a1.y + a2.y + a3.y;
        acc.z += a1.z + a2.z + a3.z;
        acc.w += a1.w + a2.w + a3.w;

        // |s|^2 across the 4 d-quads (dq = low 2 bits of lane id)
        float sq = acc.x*acc.x + acc.y*acc.y + acc.z*acc.z + acc.w*acc.w;
        sq += __shfl_xor(sq, 1);
        sq += __shfl_xor(sq, 2);
        const float scale = sq / ((1.0f + sq) * sqrtf(sq + SQ_EPS));

        if (phase == 3) {
            float4* op = reinterpret_cast<float4*>(out + ((size_t)b * NC + c) * DC + dq * 4);
            *op = make_float4(scale*acc.x, scale*acc.y, scale*acc.z, scale*acc.w);
        } else {
            const float ns = scale * (float)NI;
            float4* vp = reinterpret_cast<float4*>(
                veff + (((size_t)b * 2 + (dq >> 1)) * 32 + c) * 8 + (dq & 1) * 4);
            if (phase == 1) {
                *vp = make_float4(ns*acc.x, ns*acc.y, ns*acc.z, ns*acc.w);
            } else {
                float4 old = *vp;
                *vp = make_float4(old.x + ns*acc.x, old.y + ns*acc.y,
                                  old.z + ns*acc.z, old.w + ns*acc.w);
            }
        }
    }
}

extern "C" void kernel_launch(void* const* d_in, const int* in_sizes, int n_in,
                              void* d_out, int out_size, void* d_ws, size_t ws_size,
                              hipStream_t stream) {
    (void)in_sizes; (void)n_in; (void)out_size; (void)ws_size;
    const float* x = (const float*)d_in[0];
    const float* W = (const float*)d_in[1];

    float* partial = (float*)d_ws;      // 512 slabs x 32 KB = 16 MiB
    float* veff    = (float*)d_out;     // scratch; phase-3 squash overwrites

    const dim3 grid(128, 4);

    // ---- iteration 1: uniform coupling
    route_pass<0><<<grid, 256, 0, stream>>>(x, W, nullptr, partial);
    reduce_squash<<<64, 512, 0, stream>>>(partial, veff, nullptr, 1);

    // ---- iteration 2: logits = NI * <u, v1>
    route_pass<1><<<grid, 256, 0, stream>>>(x, W, veff, partial);
    reduce_squash<<<64, 512, 0, stream>>>(partial, veff, nullptr, 2);

    // ---- iteration 3: logits = NI * (<u, v1> + <u, v2>)
    route_pass<1><<<grid, 256, 0, stream>>>(x, W, veff, partial);
    reduce_squash<<<64, 512, 0, stream>>>(partial, nullptr, (float*)d_out, 3);
}

// Round 4
// 181.536 us; speedup vs baseline: 2.0293x; 2.0293x over previous
//
#include <hip/hip_runtime.h>

#define NI 2048
#define NB 64
#define NC 32
#define DC 16
#define DI 8

static constexpr float SQ_EPS = 1e-7f;

// SSA vector type: first-class LLVM vector -> never an alloca, never scratch.
typedef float f8 __attribute__((ext_vector_type(8)));

// Routing pass v5 — v4's small-LDS structure + v1's proven register attrs.
// v2/v3/v4 post-mortem: every "4 waves/EU" request (amdgpu_waves_per_eu(4),
// (4,4), __launch_bounds__(256,4)) produced a 64-VGPR allocation + massive
// scratch spill (FETCH 179-223 MB). Empirical law on this toolchain:
// arch-VGPR budget = 256 / min_waves_per_eu (v1: 2 -> 128 budget, 108
// alloc, no spill; 4 -> 64, spill). So we DON'T ask the compiler for
// occupancy: waves_per_eu(2,2) keeps the no-spill 108-reg codegen, and the
// HARDWARE reaches 16 waves/CU from the resource limits alone:
//   LDS 34.8 KB -> 4 blocks/CU;  108 VGPR -> floor(512/112) = 4 waves/EU.
// Structure (unchanged from v4): 8 rounds x 2 i-slots; wbuf 33.8 KB;
// xbuf staged per round (1 KB). Per-wave arithmetic, ds_read count,
// W global loads, partial layout: identical to v1.
// Grid (128 i-blocks, 4 b-quarters) x 256 threads (4 waves).
// Wave w owns b-quad by*16 + w*4 + {0..3}; every wave sweeps all 16 i.
// Lane = (c = lane&31, dg = lane>>5).
// MODE 0: uniform coupling 1/32. MODE 1: logits = dot(u, veff),
// veff transposed [b][dg][c][8].
template <int MODE>
__global__
__attribute__((amdgpu_flat_work_group_size(256, 256), amdgpu_waves_per_eu(2, 2)))
void route_pass(
    const float* __restrict__ x, const float* __restrict__ W,
    const float* __restrict__ veff, float* __restrict__ partial)
{
    // W slots: float4 [slot 2][k10 16][kdg 2][c 32 + 1 pad] stride 33.
    __shared__ float4 wbuf[2112];   // 33.8 KB
    __shared__ float4 xbuf[64];     // [brel 16][4] = 2 i x 2 f4 per b, 1 KB

    const int tid   = threadIdx.x;
    const int wave  = tid >> 6;
    const int lane  = tid & 63;
    const int c     = lane & 31;
    const int dg    = lane >> 5;
    const int brel0 = wave * 4;
    const int b0    = blockIdx.y * 16 + brel0;    // wave's b-quad base

    f8 s0 = {}, s1 = {}, s2 = {}, s3 = {};

    // veff fragments for the 4 b's (MODE 1), transposed [b][dg][c][8]
    f8 va = {}, vb = {}, vc = {}, vd = {};
    if (MODE == 1) {
        va = *reinterpret_cast<const f8*>(veff + (((size_t)(b0+0)*2 + dg)*32 + c)*8);
        vb = *reinterpret_cast<const f8*>(veff + (((size_t)(b0+1)*2 + dg)*32 + c)*8);
        vc = *reinterpret_cast<const f8*>(veff + (((size_t)(b0+2)*2 + dg)*32 + c)*8);
        vd = *reinterpret_cast<const f8*>(veff + (((size_t)(b0+3)*2 + dg)*32 + c)*8);
    }

    for (int rnd = 0; rnd < 8; ++rnd) {
        const int i0 = blockIdx.x * 16 + rnd * 2;
        __syncthreads();               // previous round's readers done
        // ---- stage W: 2 i-rows x 32 c = 64 rows x 512 B (coalesced)
        {
            const int k   = tid & 31;         // float4 within a (c,i) row
            const int p0  = tid >> 5;         // 0..7
            const int k10 = k & 15, kdg = k >> 4;
#pragma unroll
            for (int r = 0; r < 8; ++r) {
                const int row = r * 8 + p0;   // 0..63
                const int cc  = row >> 1;
                const int sub = row & 1;      // i-slot
                wbuf[((sub * 16 + k10) * 2 + kdg) * 33 + cc] =
                    reinterpret_cast<const float4*>(W)[
                        ((size_t)cc * NI + i0 + sub) * 32 + k];
            }
        }
        // ---- stage x: 16 b x 2 i x 8 f = 64 float4
        if (tid < 64) {
            const int brel = tid >> 2;
            const int q    = tid & 3;
            xbuf[tid] = reinterpret_cast<const float4*>(x)[
                ((size_t)(blockIdx.y * 16 + brel) * NI + i0) * 2 + q];
        }
        __syncthreads();

#pragma unroll
        for (int il = 0; il < 2; ++il) {
            // x broadcast reads (wave-uniform LDS addresses)
            const float4 xa0 = xbuf[(brel0+0)*4 + il*2], xa1 = xbuf[(brel0+0)*4 + il*2+1];
            const float4 xb0 = xbuf[(brel0+1)*4 + il*2], xb1 = xbuf[(brel0+1)*4 + il*2+1];
            const float4 xc0 = xbuf[(brel0+2)*4 + il*2], xc1 = xbuf[(brel0+2)*4 + il*2+1];
            const float4 xd0 = xbuf[(brel0+3)*4 + il*2], xd1 = xbuf[(brel0+3)*4 + il*2+1];

            f8 u0 = {}, u1 = {}, u2 = {}, u3 = {};
#pragma unroll
            for (int dd = 0; dd < 8; ++dd) {
                const float4 wl = wbuf[((il*16 + dd*2    )*2 + dg)*33 + c];
                const float4 wh = wbuf[((il*16 + dd*2 + 1)*2 + dg)*33 + c];
                u0[dd] = wl.x*xa0.x + wl.y*xa0.y + wl.z*xa0.z + wl.w*xa0.w
                       + wh.x*xa1.x + wh.y*xa1.y + wh.z*xa1.z + wh.w*xa1.w;
                u1[dd] = wl.x*xb0.x + wl.y*xb0.y + wl.z*xb0.z + wl.w*xb0.w
                       + wh.x*xb1.x + wh.y*xb1.y + wh.z*xb1.z + wh.w*xb1.w;
                u2[dd] = wl.x*xc0.x + wl.y*xc0.y + wl.z*xc0.z + wl.w*xc0.w
                       + wh.x*xc1.x + wh.y*xc1.y + wh.z*xc1.z + wh.w*xc1.w;
                u3[dd] = wl.x*xd0.x + wl.y*xd0.y + wl.z*xd0.z + wl.w*xd0.w
                       + wh.x*xd1.x + wh.y*xd1.y + wh.z*xd1.z + wh.w*xd1.w;
            }

            if (MODE == 0) {
                const float cu = 1.0f / 32.0f;
                s0 += u0 * cu; s1 += u1 * cu; s2 += u2 * cu; s3 += u3 * cu;
            } else {
                // Pair-softmax: lower 32-half reduces the even b, upper the
                // odd b, concurrently; one xor-32 merge in, one xor-32
                // coef-swap out. 12 shuffles + 1 exp per pair.
#pragma unroll
                for (int pr = 0; pr < 2; ++pr) {
                    const f8& ue = pr ? u2 : u0;
                    const f8& uo = pr ? u3 : u1;
                    const f8& ve = pr ? vc : va;
                    const f8& vo = pr ? vd : vb;
                    float pe = 0.0f, po = 0.0f;
#pragma unroll
                    for (int k = 0; k < 8; ++k) {
                        pe += ue[k] * ve[k];
                        po += uo[k] * vo[k];
                    }
                    // route partial of the OTHER half's b across, keep mine
                    const float send = (dg == 0) ? po : pe;
                    const float recv = __shfl_xor(send, 32);
                    float a = ((dg == 0) ? pe : po) + recv;  // full logit
                    float m = a;
#pragma unroll
                    for (int off = 16; off >= 1; off >>= 1)
                        m = fmaxf(m, __shfl_xor(m, off));
                    const float e = __expf(a - m);
                    float t = e;
#pragma unroll
                    for (int off = 16; off >= 1; off >>= 1)
                        t += __shfl_xor(t, off);
                    const float mine  = e / t;
                    const float other = __shfl_xor(mine, 32);
                    const float ce = (dg == 0) ? mine : other;
                    const float co = (dg == 0) ? other : mine;
                    if (pr == 0) { s0 += u0 * ce; s1 += u1 * co; }
                    else         { s2 += u2 * ce; s3 += u3 * co; }
                }
            }
        }
    }

    // ---- flush the wave's four s-partials (plain coalesced 32 B stores)
    // partial floats: [pblk 512][brel 16][dg 2][c 32][8]
    {
        const int pblk = blockIdx.y * gridDim.x + blockIdx.x;   // 0..511
        float* gp = partial +
            (((size_t)pblk * 16 + brel0) * 128 + dg * 64 + c * 2) * 4;
        *reinterpret_cast<f8*>(gp)        = s0;
        *reinterpret_cast<f8*>(gp +  512) = s1;
        *reinterpret_cast<f8*>(gp + 1024) = s2;
        *reinterpret_cast<f8*>(gp + 1536) = s3;
    }
}

// Fused 128-way partial reduction + squash, float4-vectorized.
// 64 blocks x 512 threads: tid -> (ibq = tid>>7 sums 32 of the 128 i-block
// slabs; sub = tid&127 -> (c = (sub>>2)&31, dq = sub&3)). 4-way LDS tree
// then squash on tid<128.
// phase 1: veff  = NI * squash(s)   (transposed layout [b][dg][c][8])
// phase 2: veff += NI * squash(s)
// phase 3: out   = squash(s)        (canonical [b][c][d])
__global__ __launch_bounds__(512) void reduce_squash(
    const float* __restrict__ partial, float* __restrict__ veff,
    float* __restrict__ out, int phase)
{
    __shared__ float4 red[512];
    const int b   = blockIdx.x;
    const int sub = threadIdx.x & 127;
    const int ibq = threadIdx.x >> 7;        // i-block quarter
    const int c   = (sub >> 2) & 31;
    const int dq  = sub & 3;                 // d-quad: d = dq*4 + j

    // slab layout: [by*128 + ib][brel 16][dg 2][c 32][8]
    const float* base = partial
        + ((size_t)(b >> 4) * 2048 + (b & 15)) * 512
        + (dq >> 1) * 256 + c * 8 + (dq & 1) * 4
        + (size_t)ibq * 32 * 8192;
    float4 acc = make_float4(0.f, 0.f, 0.f, 0.f);
#pragma unroll 8
    for (int ib = 0; ib < 32; ++ib) {
        const float4 p = *reinterpret_cast<const float4*>(base + (size_t)ib * 8192);
        acc.x += p.x; acc.y += p.y; acc.z += p.z; acc.w += p.w;
    }
    red[threadIdx.x] = acc;
    __syncthreads();
    if (threadIdx.x < 128) {
        const float4 a1 = red[sub + 128];
        const float4 a2 = red[sub + 256];
        const float4 a3 = red[sub + 384];
        acc.x += a1.x + a2.x + a3.x;
        acc.y += a1.y + a2.y + a3.y;
        acc.z += a1.z + a2.z + a3.z;
        acc.w += a1.w + a2.w + a3.w;

        // |s|^2 across the 4 d-quads (dq = low 2 bits of lane id)
        float sq = acc.x*acc.x + acc.y*acc.y + acc.z*acc.z + acc.w*acc.w;
        sq += __shfl_xor(sq, 1);
        sq += __shfl_xor(sq, 2);
        const float scale = sq / ((1.0f + sq) * sqrtf(sq + SQ_EPS));

        if (phase == 3) {
            float4* op = reinterpret_cast<float4*>(out + ((size_t)b * NC + c) * DC + dq * 4);
            *op = make_float4(scale*acc.x, scale*acc.y, scale*acc.z, scale*acc.w);
        } else {
            const float ns = scale * (float)NI;
            float4* vp = reinterpret_cast<float4*>(
                veff + (((size_t)b * 2 + (dq >> 1)) * 32 + c) * 8 + (dq & 1) * 4);
            if (phase == 1) {
                *vp = make_float4(ns*acc.x, ns*acc.y, ns*acc.z, ns*acc.w);
            } else {
                float4 old = *vp;
                *vp = make_float4(old.x + ns*acc.x, old.y + ns*acc.y,
                                  old.z + ns*acc.z, old.w + ns*acc.w);
            }
        }
    }
}

extern "C" void kernel_launch(void* const* d_in, const int* in_sizes, int n_in,
                              void* d_out, int out_size, void* d_ws, size_t ws_size,
                              hipStream_t stream) {
    (void)in_sizes; (void)n_in; (void)out_size; (void)ws_size;
    const float* x = (const float*)d_in[0];
    const float* W = (const float*)d_in[1];

    float* partial = (float*)d_ws;      // 512 slabs x 32 KB = 16 MiB
    float* veff    = (float*)d_out;     // scratch; phase-3 squash overwrites

    const dim3 grid(128, 4);

    // ---- iteration 1: uniform coupling
    route_pass<0><<<grid, 256, 0, stream>>>(x, W, nullptr, partial);
    reduce_squash<<<64, 512, 0, stream>>>(partial, veff, nullptr, 1);

    // ---- iteration 2: logits = NI * <u, v1>
    route_pass<1><<<grid, 256, 0, stream>>>(x, W, veff, partial);
    reduce_squash<<<64, 512, 0, stream>>>(partial, veff, nullptr, 2);

    // ---- iteration 3: logits = NI * (<u, v1> + <u, v2>)
    route_pass<1><<<grid, 256, 0, stream>>>(x, W, veff, partial);
    reduce_squash<<<64, 512, 0, stream>>>(partial, nullptr, (float*)d_out, 3);
}